// Round 1
// baseline (201.288 us; speedup 1.0000x reference)
//
#include <hip/hip_runtime.h>
#include <math.h>

#define NSCALES 3
#define BATCH 64
#define NBOX 32

// cells per scale (B*A*H*W for obj channel)
#define CELLS0 4915200
#define CELLS1 1228800
#define CELLS2 307200

// obj kernel partitioning: 4096 floats per block (256 thr * 4 (float4) * 4 unroll)
#define NB0 1200   // CELLS0/4096
#define NB1 300
#define NB2 75

struct Accum {
    double box_sum[3];
    double pos_sum[3];
    double neg_corr[3];
    double neg_total[3];
    int n_pos[3];
    int pad;
};

__device__ __forceinline__ float softplusf(float x) {
    // stable: max(x,0) + log1p(exp(-|x|))  == jax.nn.softplus
    return fmaxf(x, 0.0f) + log1pf(expf(-fabsf(x)));
}

// One block per (scale, batch sample). 32 lanes handle the 32 boxes:
// anchor match, target computation, duplicate-cell resolution (last write
// wins per JAX scatter semantics), then the positive-cell loss terms.
__global__ __launch_bounds__(64) void targets_kernel(
    const float* __restrict__ pred0, const float* __restrict__ pred1,
    const float* __restrict__ pred2, const float* __restrict__ boxes,
    const float* __restrict__ anchors, Accum* __restrict__ acc)
{
    const int bs = blockIdx.x;          // s*BATCH + b
    const int s  = bs / BATCH;
    const int b  = bs % BATCH;
    const int G  = (s == 0) ? 160 : (s == 1 ? 80 : 40);
    const float* __restrict__ pred = (s == 0) ? pred0 : (s == 1 ? pred1 : pred2);
    const int HW = G * G;
    const int t  = threadIdx.x;

    __shared__ int keys[NBOX];

    float sq = 0.0f, posv = 0.0f, negc = 0.0f;
    int cnt = 0;

    int key = -1;
    float gx = 0.f, gy = 0.f, gw = 1.f, gh = 1.f;
    int gi = 0, gj = 0, best = 0;

    if (t < NBOX) {
        const float4 bx = ((const float4*)boxes)[b * NBOX + t];
        const float fG = (float)G;
        gx = bx.x * fG; gy = bx.y * fG; gw = bx.z * fG; gh = bx.w * fG;
        float bestm = -1.0f;
        #pragma unroll
        for (int a = 0; a < 3; ++a) {
            float aw = anchors[s * 6 + a * 2 + 0];
            float ah = anchors[s * 6 + a * 2 + 1];
            float rw = aw / gw, rh = ah / gh;
            float m = fminf(rw, 1.0f / rw) * fminf(rh, 1.0f / rh);
            if (m > bestm) { bestm = m; best = a; }   // strict > == first argmax
        }
        gi = (int)gx;   // truncation; gx > 0 always
        gj = (int)gy;
        key = (best * G + gj) * G + gi;
        keys[t] = key;
    }
    __syncthreads();

    if (t < NBOX) {
        bool winner = true;
        for (int u = t + 1; u < NBOX; ++u)
            if (keys[u] == key) winner = false;   // later box overwrites -> last wins
        if (winner) {
            float aw = anchors[s * 6 + best * 2 + 0];
            float ah = anchors[s * 6 + best * 2 + 1];
            float tx = gx - (float)gi;
            float ty = gy - (float)gj;
            float tw = logf(gw / aw + 1e-16f);
            float th = logf(gh / ah + 1e-16f);
            size_t base = (size_t)((b * 3 + best) * 6) * (size_t)HW + (size_t)(gj * G + gi);
            float px = pred[base + (size_t)0 * HW];
            float py = pred[base + (size_t)1 * HW];
            float pw = pred[base + (size_t)2 * HW];
            float ph = pred[base + (size_t)3 * HW];
            float po = pred[base + (size_t)4 * HW];
            float dx = px - tx, dy = py - ty, dw = pw - tw, dh = ph - th;
            sq   = dx * dx + dy * dy + dw * dw + dh * dh;
            posv = softplusf(-po);
            negc = softplusf(po);   // correction: dense kernel counted this cell as negative
            cnt  = 1;
        }
    }

    // single-wave (64-lane) shuffle reduction; lanes >=32 carry zeros
    #pragma unroll
    for (int off = 32; off; off >>= 1) {
        sq   += __shfl_down(sq, off);
        posv += __shfl_down(posv, off);
        negc += __shfl_down(negc, off);
        cnt  += __shfl_down(cnt, off);
    }
    if (t == 0) {
        atomicAdd(&acc->box_sum[s],  (double)sq);
        atomicAdd(&acc->pos_sum[s],  (double)posv);
        atomicAdd(&acc->neg_corr[s], (double)negc);
        atomicAdd(&acc->n_pos[s],    cnt);
    }
}

// Dense softplus(po) sum over all obj cells of all 3 scales.
// Each block handles a 4096-float chunk of a single scale (counts divide evenly).
__global__ __launch_bounds__(256) void obj_kernel(
    const float4* __restrict__ p0, const float4* __restrict__ p1,
    const float4* __restrict__ p2, Accum* __restrict__ acc)
{
    const int blk = blockIdx.x;
    int s, HW4, base4;
    const float4* __restrict__ p;
    if (blk < NB0)            { s = 0; p = p0; HW4 = 6400; base4 = blk * 1024; }
    else if (blk < NB0 + NB1) { s = 1; p = p1; HW4 = 1600; base4 = (blk - NB0) * 1024; }
    else                      { s = 2; p = p2; HW4 = 400;  base4 = (blk - NB0 - NB1) * 1024; }

    float sum = 0.0f;
    #pragma unroll
    for (int k = 0; k < 4; ++k) {
        int i4    = base4 + k * 256 + threadIdx.x;   // float4 index within scale's obj cells
        int plane = i4 / HW4;                        // (b*3 + a)
        int off4  = i4 - plane * HW4;
        float4 v  = p[(size_t)(plane * 6 + 4) * HW4 + off4];
        sum += softplusf(v.x) + softplusf(v.y) + softplusf(v.z) + softplusf(v.w);
    }

    // block reduction: per-wave shuffle, then LDS across 4 waves
    #pragma unroll
    for (int off = 32; off; off >>= 1) sum += __shfl_down(sum, off);
    __shared__ float wsum[4];
    const int wave = threadIdx.x >> 6;
    if ((threadIdx.x & 63) == 0) wsum[wave] = sum;
    __syncthreads();
    if (threadIdx.x == 0) {
        float tot = wsum[0] + wsum[1] + wsum[2] + wsum[3];
        atomicAdd(&acc->neg_total[s], (double)tot);
    }
}

__global__ void finalize_kernel(const Accum* __restrict__ acc, float* __restrict__ out)
{
    if (threadIdx.x == 0 && blockIdx.x == 0) {
        const double cells[3] = {(double)CELLS0, (double)CELLS1, (double)CELLS2};
        double lb = 0.0, lo = 0.0;
        #pragma unroll
        for (int s = 0; s < 3; ++s) {
            double npos = (double)acc->n_pos[s];
            double nneg = cells[s] - npos;
            lb += acc->box_sum[s] / npos;
            lo += acc->pos_sum[s] / npos
                + (acc->neg_total[s] - acc->neg_corr[s]) / nneg;
        }
        out[0] = (float)(0.05 * lb + 1.0 * lo);
    }
}

extern "C" void kernel_launch(void* const* d_in, const int* in_sizes, int n_in,
                              void* d_out, int out_size, void* d_ws, size_t ws_size,
                              hipStream_t stream) {
    const float* p0      = (const float*)d_in[0];
    const float* p1      = (const float*)d_in[1];
    const float* p2      = (const float*)d_in[2];
    const float* boxes   = (const float*)d_in[3];
    // d_in[4] = labels (unused, nc==1)
    const float* anchors = (const float*)d_in[5];

    Accum* acc = (Accum*)d_ws;
    hipMemsetAsync(d_ws, 0, sizeof(Accum), stream);

    targets_kernel<<<NSCALES * BATCH, 64, 0, stream>>>(p0, p1, p2, boxes, anchors, acc);
    obj_kernel<<<NB0 + NB1 + NB2, 256, 0, stream>>>(
        (const float4*)p0, (const float4*)p1, (const float4*)p2, acc);
    finalize_kernel<<<1, 64, 0, stream>>>(acc, (float*)d_out);
}

// Round 2
// 192.423 us; speedup vs baseline: 1.0461x; 1.0461x over previous
//
#include <hip/hip_runtime.h>
#include <math.h>

// ---- static problem geometry ----
#define NB0 1200              // scale0 obj cells / 4096  (64*3*160*160 / 4096)
#define NB1 300
#define NB2 75
#define NOBJ (NB0 + NB1 + NB2)   // 1575 dense-obj blocks
#define NPAIR 192                // 3 scales * 64 batch samples
#define NTGT (NPAIR / 8)         // 24 target blocks, 8 (s,b) pairs each
#define CELLS0 4915200.0
#define CELLS1 1228800.0
#define CELLS2 307200.0

struct TgtPart { double box, pos, negc, cnt; };   // 32 B, one per (s,b) pair

__device__ __forceinline__ float softplusf(float x) {
    // stable: max(x,0) + log1p(exp(-|x|)) == jax.nn.softplus
    return fmaxf(x, 0.0f) + log1pf(expf(-fabsf(x)));
}

// Fused kernel. Blocks [0, NOBJ): dense softplus(obj) partial sums, one
// 4096-float chunk each, single-writer slot (no atomics, no init needed).
// Blocks [NOBJ, NOBJ+NTGT): anchor matching + targets, 8 (s,b) pairs per
// block (32 lanes per pair), one TgtPart slot per pair.
__global__ __launch_bounds__(256) void main_kernel(
    const float* __restrict__ p0, const float* __restrict__ p1,
    const float* __restrict__ p2, const float* __restrict__ boxes,
    const float* __restrict__ anchors,
    double* __restrict__ obj_part,      // [NOBJ]
    TgtPart* __restrict__ tgt_part)     // [NPAIR]
{
    const int blk = blockIdx.x;
    const int tid = threadIdx.x;

    if (blk < NOBJ) {
        int HW4, base4;
        const float4* __restrict__ p;
        if (blk < NB0)            { p = (const float4*)p0; HW4 = 6400; base4 = blk * 1024; }
        else if (blk < NB0 + NB1) { p = (const float4*)p1; HW4 = 1600; base4 = (blk - NB0) * 1024; }
        else                      { p = (const float4*)p2; HW4 = 400;  base4 = (blk - NB0 - NB1) * 1024; }

        float sum = 0.0f;
        #pragma unroll
        for (int k = 0; k < 4; ++k) {
            int i4    = base4 + k * 256 + tid;   // float4 idx within this scale's obj cells
            int plane = i4 / HW4;                // (b*3 + a)
            int off4  = i4 - plane * HW4;
            float4 v  = p[(size_t)(plane * 6 + 4) * HW4 + off4];
            sum += softplusf(v.x) + softplusf(v.y) + softplusf(v.z) + softplusf(v.w);
        }
        #pragma unroll
        for (int off = 32; off; off >>= 1) sum += __shfl_down(sum, off);
        __shared__ float wsum[4];
        if ((tid & 63) == 0) wsum[tid >> 6] = sum;
        __syncthreads();
        if (tid == 0)
            obj_part[blk] = (double)(wsum[0] + wsum[1] + wsum[2] + wsum[3]);
    } else {
        const int g  = tid >> 5, l = tid & 31;          // pair group, lane in pair
        const int pi = (blk - NOBJ) * 8 + g;            // 0..191, ordered s*64+b
        const int s  = pi >> 6, b = pi & 63;
        const int G  = (s == 0) ? 160 : (s == 1 ? 80 : 40);
        const float* __restrict__ pred = (s == 0) ? p0 : (s == 1 ? p1 : p2);
        const int HW = G * G;

        __shared__ int keys[8][32];

        const float4 bx = ((const float4*)boxes)[b * 32 + l];
        const float fG = (float)G;
        const float gx = bx.x * fG, gy = bx.y * fG, gw = bx.z * fG, gh = bx.w * fG;

        int best = 0; float bestm = -1.0f;
        #pragma unroll
        for (int a = 0; a < 3; ++a) {
            float aw = anchors[s * 6 + a * 2 + 0];
            float ah = anchors[s * 6 + a * 2 + 1];
            float rw = aw / gw, rh = ah / gh;
            float m = fminf(rw, 1.0f / rw) * fminf(rh, 1.0f / rh);
            if (m > bestm) { bestm = m; best = a; }     // strict > == first argmax
        }
        const int gi = (int)gx, gj = (int)gy;           // truncation (coords > 0)
        const int key = (best * G + gj) * G + gi;
        keys[g][l] = key;
        __syncthreads();

        float sq = 0.0f, posv = 0.0f, negc = 0.0f; int cnt = 0;
        bool winner = true;                              // last duplicate wins (JAX scatter)
        for (int u = l + 1; u < 32; ++u)
            if (keys[g][u] == key) winner = false;
        if (winner) {
            float aw = anchors[s * 6 + best * 2 + 0];
            float ah = anchors[s * 6 + best * 2 + 1];
            float tx = gx - (float)gi, ty = gy - (float)gj;
            float tw = logf(gw / aw + 1e-16f), th = logf(gh / ah + 1e-16f);
            size_t base = (size_t)((b * 3 + best) * 6) * (size_t)HW + (size_t)(gj * G + gi);
            float px = pred[base + (size_t)0 * HW];
            float py = pred[base + (size_t)1 * HW];
            float pw = pred[base + (size_t)2 * HW];
            float ph = pred[base + (size_t)3 * HW];
            float po = pred[base + (size_t)4 * HW];
            float dx = px - tx, dy = py - ty, dw = pw - tw, dh = ph - th;
            sq   = dx * dx + dy * dy + dw * dw + dh * dh;
            posv = softplusf(-po);
            negc = softplusf(po);    // dense pass counted this cell as negative
            cnt  = 1;
        }

        float fcnt = (float)cnt;
        #pragma unroll
        for (int off = 16; off; off >>= 1) {             // width-32: stay inside the pair
            sq   += __shfl_down(sq,   off, 32);
            posv += __shfl_down(posv, off, 32);
            negc += __shfl_down(negc, off, 32);
            fcnt += __shfl_down(fcnt, off, 32);
        }
        if (l == 0) {
            TgtPart t; t.box = sq; t.pos = posv; t.negc = negc; t.cnt = fcnt;
            tgt_part[pi] = t;
        }
    }
}

// Single block: waves 0-2 sum obj partials per scale; wave 3 reduces the 192
// per-pair target partials (slot/64 == scale by construction); lane 0 combines.
__global__ __launch_bounds__(256) void finalize_kernel(
    const double* __restrict__ obj_part, const TgtPart* __restrict__ tgt_part,
    float* __restrict__ out)
{
    __shared__ double negtot_s[3], box_s[3], pos_s[3], negc_s[3], cnt_s[3];
    const int tid = threadIdx.x;
    const int wave = tid >> 6, lane = tid & 63;

    if (wave < 3) {
        const int start = (wave == 0) ? 0   : (wave == 1 ? NB0       : NB0 + NB1);
        const int end   = (wave == 0) ? NB0 : (wave == 1 ? NB0 + NB1 : NOBJ);
        double sum = 0.0;
        for (int i = start + lane; i < end; i += 64) sum += obj_part[i];
        #pragma unroll
        for (int off = 32; off; off >>= 1) sum += __shfl_down(sum, off);
        if (lane == 0) negtot_s[wave] = sum;
    } else {
        double bx[3], ps[3], ng[3], ct[3];
        #pragma unroll
        for (int q = 0; q < 3; ++q) {
            TgtPart t = tgt_part[lane + 64 * q];   // slot/64 == scale q
            bx[q] = t.box; ps[q] = t.pos; ng[q] = t.negc; ct[q] = t.cnt;
        }
        #pragma unroll
        for (int off = 32; off; off >>= 1) {
            #pragma unroll
            for (int q = 0; q < 3; ++q) {
                bx[q] += __shfl_down(bx[q], off);
                ps[q] += __shfl_down(ps[q], off);
                ng[q] += __shfl_down(ng[q], off);
                ct[q] += __shfl_down(ct[q], off);
            }
        }
        if (lane == 0) {
            #pragma unroll
            for (int q = 0; q < 3; ++q) {
                box_s[q] = bx[q]; pos_s[q] = ps[q]; negc_s[q] = ng[q]; cnt_s[q] = ct[q];
            }
        }
    }
    __syncthreads();
    if (tid == 0) {
        const double cells[3] = {CELLS0, CELLS1, CELLS2};
        double lb = 0.0, lo = 0.0;
        #pragma unroll
        for (int s = 0; s < 3; ++s) {
            double npos = cnt_s[s];
            double nneg = cells[s] - npos;
            lb += box_s[s] / npos;
            lo += pos_s[s] / npos + (negtot_s[s] - negc_s[s]) / nneg;
        }
        out[0] = (float)(0.05 * lb + 1.0 * lo);
    }
}

extern "C" void kernel_launch(void* const* d_in, const int* in_sizes, int n_in,
                              void* d_out, int out_size, void* d_ws, size_t ws_size,
                              hipStream_t stream) {
    const float* p0      = (const float*)d_in[0];
    const float* p1      = (const float*)d_in[1];
    const float* p2      = (const float*)d_in[2];
    const float* boxes   = (const float*)d_in[3];
    // d_in[4] = labels (unused, nc==1)
    const float* anchors = (const float*)d_in[5];

    double*  obj_part = (double*)d_ws;                                  // NOBJ doubles
    TgtPart* tgt_part = (TgtPart*)((char*)d_ws + NOBJ * sizeof(double)); // NPAIR slots
    // every slot is written unconditionally each call -> no zero-init needed

    main_kernel<<<NOBJ + NTGT, 256, 0, stream>>>(p0, p1, p2, boxes, anchors,
                                                 obj_part, tgt_part);
    finalize_kernel<<<1, 256, 0, stream>>>(obj_part, tgt_part, (float*)d_out);
}